// Round 9
// baseline (220.646 us; speedup 1.0000x reference)
//
#include <hip/hip_runtime.h>
#include <math.h>

// ---------- types ----------
typedef __attribute__((ext_vector_type(8))) short bf16x8;   // 8 x bf16
typedef __attribute__((ext_vector_type(4))) float f32x4;

#define AS1(p) ((__attribute__((address_space(1))) void*)(uintptr_t)(p))
#define AS3(p) ((__attribute__((address_space(3))) void*)(p))

static __device__ __forceinline__ unsigned short f2bf(float f) {
    unsigned int u = __float_as_uint(f);
    unsigned int r = (u + 0x7fffu + ((u >> 16) & 1u)) >> 16;   // RNE
    return (unsigned short)r;
}

// ---------- sizes ----------
#define NPATCH 8191
#define NTOK   8192          // with cls row 0
#define INDIM  1024
#define EMBED  512

// ============================================================
// 1) k_misc: q0 partials + inits + W1 transpose (as R8)
// ============================================================
__global__ void k_misc(const float* __restrict__ W1, unsigned short* __restrict__ w1t,
                       const float* __restrict__ cls, const float* __restrict__ Wq,
                       const float* __restrict__ bv, const float* __restrict__ bo,
                       float* __restrict__ q0, float* __restrict__ h_full,
                       float* __restrict__ attn0, float* __restrict__ r0) {
    const int b = blockIdx.x;
    const int t = threadIdx.x;
    if (b < 32) {
        const float* wr = Wq + (size_t)(b * 16) * EMBED;
        float a0 = 0.f, a1 = 0.f;
        #pragma unroll
        for (int r = 0; r < 16; ++r) {
            const float c = cls[b * 16 + r];
            a0 = fmaf(c, wr[r * EMBED + t], a0);
            a1 = fmaf(c, wr[r * EMBED + t + 256], a1);
        }
        atomicAdd(&q0[t], a0);
        atomicAdd(&q0[t + 256], a1);
    } else if (b == 32) {
        const float c0 = cls[t], c1 = cls[t + 256];
        h_full[t]     = c0;       h_full[t + 256] = c1;
        attn0[t]      = bv[t];    attn0[t + 256]  = bv[t + 256];
        r0[t]         = c0 + bo[t];  r0[t + 256]  = c1 + bo[t + 256];
    } else {
        __shared__ float tile[32][33];
        const int bb = b - 33;
        const int bk = bb >> 4;
        const int bn = bb & 15;
        const int r  = t >> 3;
        const int c4 = (t & 7) * 4;
        float4 v = *(const float4*)(W1 + (size_t)(bk * 32 + r) * EMBED + bn * 32 + c4);
        tile[r][c4 + 0] = v.x; tile[r][c4 + 1] = v.y; tile[r][c4 + 2] = v.z; tile[r][c4 + 3] = v.w;
        __syncthreads();
        ushort4 o;
        o.x = f2bf(tile[c4 + 0][r]); o.y = f2bf(tile[c4 + 1][r]);
        o.z = f2bf(tile[c4 + 2][r]); o.w = f2bf(tile[c4 + 3][r]);
        *(ushort4*)(w1t + (size_t)(bn * 32 + r) * INDIM + bk * 32 + c4) = o;
    }
}

// ============================================================
// 2) k_conv: x (f32) -> xb (bf16), 8 indep float4 loads/thread
// ============================================================
__global__ void k_conv(const float* __restrict__ x, unsigned short* __restrict__ xb) {
    const int base = blockIdx.x * 2048 + threadIdx.x;
    const int NV   = NPATCH * INDIM / 4;
    const float4* x4 = (const float4*)x;
    ushort4* xb4 = (ushort4*)xb;
    float4 vv[8];
    #pragma unroll
    for (int k = 0; k < 8; ++k) {
        const int i = base + k * 256;
        if (i < NV) vv[k] = x4[i];
        else        vv[k] = make_float4(0.f, 0.f, 0.f, 0.f);
    }
    #pragma unroll
    for (int k = 0; k < 8; ++k) {
        ushort4 o;
        o.x = f2bf(vv[k].x); o.y = f2bf(vv[k].y);
        o.z = f2bf(vv[k].z); o.w = f2bf(vv[k].w);
        xb4[base + k * 256] = o;
    }
}

// ============================================================
// 3) u[in] = Wk[in,:] . (q0 + bq)
// ============================================================
__global__ void k_u(const float* __restrict__ Wk, const float* __restrict__ q0,
                    const float* __restrict__ bq, float* __restrict__ u) {
    const int wave = blockIdx.x * 4 + (threadIdx.x >> 6);
    const int lane = threadIdx.x & 63;
    const float4* q4 = (const float4*)q0;
    const float4* b4 = (const float4*)bq;
    float4 qa = q4[lane * 2], qb = q4[lane * 2 + 1];
    float4 ba = b4[lane * 2], bb = b4[lane * 2 + 1];
    qa.x += ba.x; qa.y += ba.y; qa.z += ba.z; qa.w += ba.w;
    qb.x += bb.x; qb.y += bb.y; qb.z += bb.z; qb.w += bb.w;
    for (int rr = 0; rr < 4; ++rr) {
        const int row = wave * 4 + rr;
        const float4* wr = (const float4*)(Wk + (size_t)row * EMBED);
        float4 a = wr[lane * 2], b = wr[lane * 2 + 1];
        float acc = a.x*qa.x + a.y*qa.y + a.z*qa.z + a.w*qa.w
                  + b.x*qb.x + b.y*qb.y + b.z*qb.z + b.w*qb.w;
        for (int off = 32; off; off >>= 1) acc += __shfl_down(acc, off);
        if (lane == 0) u[row] = acc;
    }
}

// ============================================================
// 4a) PROBE GEMMs (h_full only; overwritten by final k_gemm).
//     MODE 1: no-dbuf serial stage->compute
//     MODE 2: compute-only (stage 2 bufs once; clobber per kt)
//     MODE 3: stage-only (token LDS read)
// ============================================================
template<int MODE>
__global__ __launch_bounds__(256) void k_gemm_probe(const unsigned short* __restrict__ xb,
                                                    const unsigned short* __restrict__ w1t,
                                                    const float* __restrict__ b1,
                                                    float* __restrict__ h_full) {
    __shared__ __align__(16) unsigned short As[2][128 * 128];
    __shared__ __align__(16) unsigned short Bs[2][128 * 128];
    const int tid  = threadIdx.x;
    const int wave = tid >> 6;
    const int lane = tid & 63;
    const int bid  = blockIdx.x;
    const int rg   = (bid & 7) | ((bid >> 5) << 3);
    const int cg   = (bid >> 3) & 3;
    const int wr   = wave >> 1, wc = wave & 1;
    const int fr   = lane & 15, fq = lane >> 4;

    size_t srcA[8], srcB[8];
    int dstc[8];
    #pragma unroll
    for (int i = 0; i < 8; ++i) {
        const int c0  = (i * 4 + wave) * 64;
        const int c   = c0 + lane;
        const int row = c >> 4, koct = c & 15;
        const int kg  = koct ^ (row & 7);
        dstc[i] = c0 * 8;
        srcA[i] = (size_t)(rg * 128 + row) * INDIM + kg * 8;
        srcB[i] = (size_t)(cg * 128 + row) * INDIM + kg * 8;
    }

    f32x4 acc[4][4] = {};

    int aoff[4], boff[4];
    #pragma unroll
    for (int mi = 0; mi < 4; ++mi) {
        const int row = wr * 64 + mi * 16 + fr;
        aoff[mi] = row * 128 + ((fq ^ (row & 7)) * 8);
        const int col = wc * 64 + mi * 16 + fr;
        boff[mi] = col * 128 + ((fq ^ (col & 7)) * 8);
    }

#define STAGE(buf, k0) do { \
    _Pragma("unroll") \
    for (int i = 0; i < 8; ++i) \
        __builtin_amdgcn_global_load_lds(AS1(xb + srcA[i] + (k0)), \
                                         AS3(&As[buf][dstc[i]]), 16, 0, 0); \
    _Pragma("unroll") \
    for (int i = 0; i < 8; ++i) \
        __builtin_amdgcn_global_load_lds(AS1(w1t + srcB[i] + (k0)), \
                                         AS3(&Bs[buf][dstc[i]]), 16, 0, 0); \
    } while (0)

    if (MODE == 1) {
        // serial: stage -> barrier -> compute -> barrier, single buffer
        for (int kt = 0; kt < 8; ++kt) {
            __syncthreads();
            STAGE(0, kt * 128);
            __syncthreads();
            #pragma unroll
            for (int kk = 0; kk < 4; ++kk) {
                bf16x8 af[4], bf[4];
                #pragma unroll
                for (int mi = 0; mi < 4; ++mi)
                    af[mi] = *(const bf16x8*)&As[0][aoff[mi] ^ (kk * 32)];
                #pragma unroll
                for (int ni = 0; ni < 4; ++ni)
                    bf[ni] = *(const bf16x8*)&Bs[0][boff[ni] ^ (kk * 32)];
                #pragma unroll
                for (int mi = 0; mi < 4; ++mi)
                    #pragma unroll
                    for (int ni = 0; ni < 4; ++ni)
                        acc[mi][ni] = __builtin_amdgcn_mfma_f32_16x16x32_bf16(af[mi], bf[ni], acc[mi][ni], 0, 0, 0);
            }
        }
    } else if (MODE == 2) {
        // compute-only: stage both buffers once, then 8 kt of pure LDS+MFMA
        STAGE(0, 0);
        STAGE(1, 128);
        __syncthreads();
        for (int kt = 0; kt < 8; ++kt) {
            const int cur = kt & 1;
            asm volatile("" ::: "memory");   // force LDS re-reads each kt
            #pragma unroll
            for (int kk = 0; kk < 4; ++kk) {
                bf16x8 af[4], bf[4];
                #pragma unroll
                for (int mi = 0; mi < 4; ++mi)
                    af[mi] = *(const bf16x8*)&As[cur][aoff[mi] ^ (kk * 32)];
                #pragma unroll
                for (int ni = 0; ni < 4; ++ni)
                    bf[ni] = *(const bf16x8*)&Bs[cur][boff[ni] ^ (kk * 32)];
                #pragma unroll
                for (int mi = 0; mi < 4; ++mi)
                    #pragma unroll
                    for (int ni = 0; ni < 4; ++ni)
                        acc[mi][ni] = __builtin_amdgcn_mfma_f32_16x16x32_bf16(af[mi], bf[ni], acc[mi][ni], 0, 0, 0);
            }
            __syncthreads();
        }
    } else {
        // stage-only: R8 schedule without MFMA; token read keeps LDS live
        STAGE(0, 0);
        __syncthreads();
        int cur = 0;
        for (int kt = 0; kt < 8; ++kt) {
            if (kt < 7) STAGE(cur ^ 1, (kt + 1) * 128);
            asm volatile("" ::: "memory");
            short tok = As[cur][(aoff[0] + kt) & 16383] + Bs[cur][(boff[0] + kt) & 16383];
            acc[0][0][0] += (float)tok;
            __syncthreads();
            cur ^= 1;
        }
    }
#undef STAGE

    float bvv[4];
    #pragma unroll
    for (int ni = 0; ni < 4; ++ni)
        bvv[ni] = b1[cg * 128 + wc * 64 + ni * 16 + fr];
    #pragma unroll
    for (int mi = 0; mi < 4; ++mi) {
        #pragma unroll
        for (int rr = 0; rr < 4; ++rr) {
            const int a = rg * 128 + wr * 64 + mi * 16 + fq * 4 + rr;
            if (a < NPATCH) {
                #pragma unroll
                for (int ni = 0; ni < 4; ++ni) {
                    const int col = cg * 128 + wc * 64 + ni * 16 + fr;
                    h_full[(size_t)(a + 1) * EMBED + col] = fmaxf(acc[mi][ni][rr] + bvv[ni], 0.f);
                }
            }
        }
    }
}

// ============================================================
// 4b) k_gemm_occ: candidate fix. 128x64 tiles, BK=64, 48KB LDS,
//     grid 512 -> 3 blocks/CU. XCD-chunked. h_full only (probe).
// ============================================================
__global__ __launch_bounds__(256) void k_gemm_occ(const unsigned short* __restrict__ xb,
                                                  const unsigned short* __restrict__ w1t,
                                                  const float* __restrict__ b1,
                                                  float* __restrict__ h_full) {
    __shared__ __align__(16) unsigned short As[2][128 * 64];   // 16 KB x2
    __shared__ __align__(16) unsigned short Bs[2][64 * 64];    // 8 KB x2
    const int tid  = threadIdx.x;
    const int wave = tid >> 6;
    const int lane = tid & 63;
    const int bid  = blockIdx.x;
    const int T    = ((bid & 7) << 6) | (bid >> 3);   // bijective, 512%8==0
    const int rg   = T >> 3;                          // 0..63
    const int cg   = T & 7;                           // 0..7
    const int fr   = lane & 15, fq = lane >> 4;

    // A: 1024 chunks (row=c>>3 0..127, koct=c&7), 4 issues/thread
    // B: 512 chunks (row=c>>3 0..63), 2 issues/thread
    size_t srcA[4], srcB[2];
    int dstA[4], dstB[2];
    #pragma unroll
    for (int i = 0; i < 4; ++i) {
        const int c0 = i * 256 + wave * 64;
        const int c  = c0 + lane;
        const int row = c >> 3, koct = c & 7;
        const int kg = koct ^ (row & 7);
        dstA[i] = c0 * 8;
        srcA[i] = (size_t)(rg * 128 + row) * INDIM + kg * 8;
    }
    #pragma unroll
    for (int i = 0; i < 2; ++i) {
        const int c0 = i * 256 + wave * 64;
        const int c  = c0 + lane;
        const int row = c >> 3, koct = c & 7;
        const int kg = koct ^ (row & 7);
        dstB[i] = c0 * 8;
        srcB[i] = (size_t)(cg * 64 + row) * INDIM + kg * 8;
    }

    f32x4 acc[2][4] = {};

    int aoff[2], boff[4];
    #pragma unroll
    for (int mi = 0; mi < 2; ++mi) {
        const int row = wave * 32 + mi * 16 + fr;
        aoff[mi] = row * 64 + ((fq ^ (row & 7)) * 8);
    }
    #pragma unroll
    for (int ni = 0; ni < 4; ++ni) {
        const int col = ni * 16 + fr;
        boff[ni] = col * 64 + ((fq ^ (col & 7)) * 8);
    }

#define STAGEO(buf, k0) do { \
    _Pragma("unroll") \
    for (int i = 0; i < 4; ++i) \
        __builtin_amdgcn_global_load_lds(AS1(xb + srcA[i] + (k0)), \
                                         AS3(&As[buf][dstA[i]]), 16, 0, 0); \
    _Pragma("unroll") \
    for (int i = 0; i < 2; ++i) \
        __builtin_amdgcn_global_load_lds(AS1(w1t + srcB[i] + (k0)), \
                                         AS3(&Bs[buf][dstB[i]]), 16, 0, 0); \
    } while (0)

    STAGEO(0, 0);
    __syncthreads();

    int cur = 0;
    for (int kt = 0; kt < 16; ++kt) {
        if (kt < 15) STAGEO(cur ^ 1, (kt + 1) * 64);
        #pragma unroll
        for (int kk = 0; kk < 2; ++kk) {
            bf16x8 af[2], bf[4];
            #pragma unroll
            for (int mi = 0; mi < 2; ++mi)
                af[mi] = *(const bf16x8*)&As[cur][aoff[mi] ^ (kk * 32)];
            #pragma unroll
            for (int ni = 0; ni < 4; ++ni)
                bf[ni] = *(const bf16x8*)&Bs[cur][boff[ni] ^ (kk * 32)];
            #pragma unroll
            for (int mi = 0; mi < 2; ++mi)
                #pragma unroll
                for (int ni = 0; ni < 4; ++ni)
                    acc[mi][ni] = __builtin_amdgcn_mfma_f32_16x16x32_bf16(af[mi], bf[ni], acc[mi][ni], 0, 0, 0);
        }
        __syncthreads();
        cur ^= 1;
    }
#undef STAGEO

    float bvv[4];
    #pragma unroll
    for (int ni = 0; ni < 4; ++ni)
        bvv[ni] = b1[cg * 64 + ni * 16 + fr];
    #pragma unroll
    for (int mi = 0; mi < 2; ++mi) {
        #pragma unroll
        for (int rr = 0; rr < 4; ++rr) {
            const int a = rg * 128 + wave * 32 + mi * 16 + fq * 4 + rr;
            if (a < NPATCH) {
                #pragma unroll
                for (int ni = 0; ni < 4; ++ni) {
                    const int col = cg * 64 + ni * 16 + fr;
                    h_full[(size_t)(a + 1) * EMBED + col] = fmaxf(acc[mi][ni][rr] + bvv[ni], 0.f);
                }
            }
        }
    }
}

// ============================================================
// 4c) FINAL k_gemm (R8, authoritative: h_full + fused scores)
// ============================================================
__global__ __launch_bounds__(256) void k_gemm(const unsigned short* __restrict__ xb,
                                              const unsigned short* __restrict__ w1t,
                                              const float* __restrict__ b1,
                                              const float* __restrict__ u,
                                              float* __restrict__ h_full,
                                              float* __restrict__ scores) {
    __shared__ __align__(16) unsigned short As[2][128 * 128];
    __shared__ __align__(16) unsigned short Bs[2][128 * 128];
    const int tid  = threadIdx.x;
    const int wave = tid >> 6;
    const int lane = tid & 63;
    const int bid  = blockIdx.x;
    const int rg   = (bid & 7) | ((bid >> 5) << 3);
    const int cg   = (bid >> 3) & 3;
    const int wr   = wave >> 1, wc = wave & 1;
    const int fr   = lane & 15, fq = lane >> 4;

    size_t srcA[8], srcB[8];
    int dstc[8];
    #pragma unroll
    for (int i = 0; i < 8; ++i) {
        const int c0  = (i * 4 + wave) * 64;
        const int c   = c0 + lane;
        const int row = c >> 4, koct = c & 15;
        const int kg  = koct ^ (row & 7);
        dstc[i] = c0 * 8;
        srcA[i] = (size_t)(rg * 128 + row) * INDIM + kg * 8;
        srcB[i] = (size_t)(cg * 128 + row) * INDIM + kg * 8;
    }

    f32x4 acc[4][4] = {};

    int aoff[4], boff[4];
    #pragma unroll
    for (int mi = 0; mi < 4; ++mi) {
        const int row = wr * 64 + mi * 16 + fr;
        aoff[mi] = row * 128 + ((fq ^ (row & 7)) * 8);
        const int col = wc * 64 + mi * 16 + fr;
        boff[mi] = col * 128 + ((fq ^ (col & 7)) * 8);
    }

#define STAGE(buf, k0) do { \
    _Pragma("unroll") \
    for (int i = 0; i < 8; ++i) \
        __builtin_amdgcn_global_load_lds(AS1(xb + srcA[i] + (k0)), \
                                         AS3(&As[buf][dstc[i]]), 16, 0, 0); \
    _Pragma("unroll") \
    for (int i = 0; i < 8; ++i) \
        __builtin_amdgcn_global_load_lds(AS1(w1t + srcB[i] + (k0)), \
                                         AS3(&Bs[buf][dstc[i]]), 16, 0, 0); \
    } while (0)

    STAGE(0, 0);
    __syncthreads();

    int cur = 0;
    for (int kt = 0; kt < 8; ++kt) {
        if (kt < 7) STAGE(cur ^ 1, (kt + 1) * 128);
        #pragma unroll
        for (int kk = 0; kk < 4; ++kk) {
            bf16x8 af[4], bf[4];
            #pragma unroll
            for (int mi = 0; mi < 4; ++mi)
                af[mi] = *(const bf16x8*)&As[cur][aoff[mi] ^ (kk * 32)];
            #pragma unroll
            for (int ni = 0; ni < 4; ++ni)
                bf[ni] = *(const bf16x8*)&Bs[cur][boff[ni] ^ (kk * 32)];
            #pragma unroll
            for (int mi = 0; mi < 4; ++mi)
                #pragma unroll
                for (int ni = 0; ni < 4; ++ni)
                    acc[mi][ni] = __builtin_amdgcn_mfma_f32_16x16x32_bf16(af[mi], bf[ni], acc[mi][ni], 0, 0, 0);
        }
        __syncthreads();
        cur ^= 1;
    }
#undef STAGE

    float uv[4], bvv[4];
    #pragma unroll
    for (int ni = 0; ni < 4; ++ni) {
        const int col = cg * 128 + wc * 64 + ni * 16 + fr;
        uv[ni]  = u[col];
        bvv[ni] = b1[col];
    }
    #pragma unroll
    for (int mi = 0; mi < 4; ++mi) {
        #pragma unroll
        for (int rr = 0; rr < 4; ++rr) {
            const int a = rg * 128 + wr * 64 + mi * 16 + fq * 4 + rr;
            if (a < NPATCH) {
                float sc = 0.f;
                #pragma unroll
                for (int ni = 0; ni < 4; ++ni) {
                    const int col = cg * 128 + wc * 64 + ni * 16 + fr;
                    float v = fmaxf(acc[mi][ni][rr] + bvv[ni], 0.f);
                    h_full[(size_t)(a + 1) * EMBED + col] = v;
                    sc = fmaf(v, uv[ni], sc);
                }
                sc += __shfl_xor(sc, 1);
                sc += __shfl_xor(sc, 2);
                sc += __shfl_xor(sc, 4);
                sc += __shfl_xor(sc, 8);
                if (fr == 0) atomicAdd(&scores[a + 1], sc);
            }
        }
    }
}

// ============================================================
// 5) FUSED softmax + wsum (as R8)
// ============================================================
__global__ void k_wsum(const float* __restrict__ scores, const float* __restrict__ h_full,
                       const float* __restrict__ u, const float* __restrict__ cls,
                       float* __restrict__ svec) {
    __shared__ float redf[4];
    __shared__ float wloc[32];
    const int b = blockIdx.x, t = threadIdx.x;
    const int wv = t >> 6, lane = t & 63;
    const float rs = 0.04419417382415922f;

    float part = cls[t] * u[t] + cls[t + 256] * u[t + 256];
    for (int off = 32; off; off >>= 1) part += __shfl_down(part, off);
    if (lane == 0) redf[wv] = part;
    __syncthreads();
    const float s0 = (redf[0] + redf[1] + redf[2] + redf[3]) * rs;
    __syncthreads();

    float v[32];
    const float4* s4 = (const float4*)(scores + t * 32);
    #pragma unroll
    for (int q = 0; q < 8; ++q) {
        float4 a = s4[q];
        v[q*4+0] = a.x*rs; v[q*4+1] = a.y*rs; v[q*4+2] = a.z*rs; v[q*4+3] = a.w*rs;
    }
    if (t == 0) v[0] = s0;

    float mx = v[0];
    #pragma unroll
    for (int j = 1; j < 32; ++j) mx = fmaxf(mx, v[j]);
    mx = fmaxf(mx, __shfl_xor(mx, 1));
    mx = fmaxf(mx, __shfl_xor(mx, 2));
    mx = fmaxf(mx, __shfl_xor(mx, 4));
    mx = fmaxf(mx, __shfl_xor(mx, 8));
    float sm = 0.f;
    #pragma unroll
    for (int j = 0; j < 32; ++j) { v[j] = __expf(v[j] - mx); sm += v[j]; }
    sm += __shfl_xor(sm, 1);
    sm += __shfl_xor(sm, 2);
    sm += __shfl_xor(sm, 4);
    sm += __shfl_xor(sm, 8);
    const float inv = 1.f / sm;
    #pragma unroll
    for (int j = 0; j < 32; ++j) v[j] *= inv;

    float m2 = v[0];
    #pragma unroll
    for (int j = 1; j < 32; ++j) m2 = fmaxf(m2, v[j]);
    for (int off = 32; off; off >>= 1) m2 = fmaxf(m2, __shfl_xor(m2, off));
    if (lane == 0) redf[wv] = m2;
    __syncthreads();
    const float gm = fmaxf(fmaxf(redf[0], redf[1]), fmaxf(redf[2], redf[3]));
    __syncthreads();
    float s2 = 0.f;
    #pragma unroll
    for (int j = 0; j < 32; ++j) { v[j] = __expf(v[j] - gm); s2 += v[j]; }
    for (int off = 32; off; off >>= 1) s2 += __shfl_xor(s2, off);
    if (lane == 0) redf[wv] = s2;
    __syncthreads();
    const float gi = 1.f / (redf[0] + redf[1] + redf[2] + redf[3]);

    if (t == b) {
        #pragma unroll
        for (int j = 0; j < 32; ++j) wloc[j] = v[j] * gi;
    }
    __syncthreads();

    float a0 = 0.f, a1 = 0.f;
    #pragma unroll 4
    for (int j = 0; j < 32; ++j) {
        const float wj = wloc[j];
        const float* hr = h_full + (size_t)(b * 32 + j) * EMBED;
        a0 = fmaf(wj, hr[t], a0);
        a1 = fmaf(wj, hr[t + 256], a1);
    }
    atomicAdd(&svec[t], a0);
    atomicAdd(&svec[t + 256], a1);
}

// ============================================================
// 6/7/8) tail (as R8)
// ============================================================
__global__ void k_attn0(const float* __restrict__ svec, const float* __restrict__ Wv,
                        float* __restrict__ attn0) {
    const int b = blockIdx.x, t = threadIdx.x;
    float a0 = 0.f, a1 = 0.f;
    const int e0 = b * 16;
    #pragma unroll
    for (int e = e0; e < e0 + 16; ++e) {
        const float s = svec[e];
        const float* wr = Wv + (size_t)e * EMBED;
        a0 = fmaf(s, wr[t], a0);
        a1 = fmaf(s, wr[t + 256], a1);
    }
    atomicAdd(&attn0[t], a0);
    atomicAdd(&attn0[t + 256], a1);
}

__global__ void k_r0(const float* __restrict__ attn0, const float* __restrict__ Wo,
                     float* __restrict__ r0) {
    const int b = blockIdx.x, t = threadIdx.x;
    float a0 = 0.f, a1 = 0.f;
    const int e0 = b * 16;
    #pragma unroll
    for (int e = e0; e < e0 + 16; ++e) {
        const float s = attn0[e];
        const float* wr = Wo + (size_t)e * EMBED;
        a0 = fmaf(s, wr[t], a0);
        a1 = fmaf(s, wr[t + 256], a1);
    }
    atomicAdd(&r0[t], a0);
    atomicAdd(&r0[t + 256], a1);
}

__global__ void k_final(const float* __restrict__ r0, const float* __restrict__ ln_g,
                        const float* __restrict__ ln_b, const float* __restrict__ Wc,
                        const float* __restrict__ bc, float* __restrict__ out) {
    __shared__ float red[8];
    const int t = threadIdx.x, wv = t >> 6, lane = t & 63;
    const float x = r0[t];

    float sm = x;
    for (int off = 32; off; off >>= 1) sm += __shfl_down(sm, off);
    if (lane == 0) red[wv] = sm;
    __syncthreads();
    float mu = 0.f;
    for (int i = 0; i < 8; ++i) mu += red[i];
    mu *= (1.f / 512.f);
    const float dx = x - mu;

    __syncthreads();
    float q = dx * dx;
    for (int off = 32; off; off >>= 1) q += __shfl_down(q, off);
    if (lane == 0) red[wv] = q;
    __syncthreads();
    float var = 0.f;
    for (int i = 0; i < 8; ++i) var += red[i];
    var *= (1.f / 512.f);

    const float hn = dx / sqrtf(var + 1e-5f) * ln_g[t] + ln_b[t];
    float p0 = hn * Wc[2 * t];
    float p1 = hn * Wc[2 * t + 1];

    __syncthreads();
    for (int off = 32; off; off >>= 1) p0 += __shfl_down(p0, off);
    if (lane == 0) red[wv] = p0;
    __syncthreads();
    if (t == 0) {
        float tot = 0.f;
        for (int i = 0; i < 8; ++i) tot += red[i];
        out[0] = tot + bc[0];
    }
    __syncthreads();
    for (int off = 32; off; off >>= 1) p1 += __shfl_down(p1, off);
    if (lane == 0) red[wv] = p1;
    __syncthreads();
    if (t == 0) {
        float tot = 0.f;
        for (int i = 0; i < 8; ++i) tot += red[i];
        out[1] = tot + bc[1];
    }
}

// ============================================================
extern "C" void kernel_launch(void* const* d_in, const int* in_sizes, int n_in,
                              void* d_out, int out_size, void* d_ws, size_t ws_size,
                              hipStream_t stream) {
    const float* x    = (const float*)d_in[0];
    const float* W1   = (const float*)d_in[1];
    const float* b1   = (const float*)d_in[2];
    const float* cls  = (const float*)d_in[3];
    const float* Wq   = (const float*)d_in[4];
    const float* bq   = (const float*)d_in[5];
    const float* Wk   = (const float*)d_in[6];
    const float* bk   = (const float*)d_in[7];   (void)bk;
    const float* Wv   = (const float*)d_in[8];
    const float* bv   = (const float*)d_in[9];
    const float* Wo   = (const float*)d_in[10];
    const float* bo   = (const float*)d_in[11];
    const float* ln_g = (const float*)d_in[12];
    const float* ln_b = (const float*)d_in[13];
    const float* Wc   = (const float*)d_in[14];
    const float* bc   = (const float*)d_in[15];
    float* out = (float*)d_out;

    char* ws = (char*)d_ws;
    unsigned short* xb     = (unsigned short*)(ws);                    // 16 MB
    unsigned short* w1t    = (unsigned short*)(ws + 16777216);         // 1 MB
    float*          h_full = (float*)(ws + 17825792);                  // 16 MB
    float*          scores = (float*)(ws + 34603008);                  // 32 KB
    float*          q0     = (float*)(ws + 34635776);                  // 2 KB
    float*          svec   = (float*)(ws + 34637824);                  // 2 KB
    float*          attn0  = (float*)(ws + 34639872);
    float*          r0     = (float*)(ws + 34641920);
    float*          u      = (float*)(ws + 34643968);

    hipMemsetAsync(scores, 0, (8192 + 512 + 512) * sizeof(float), stream);
    k_misc  <<<545,  256, 0, stream>>>(W1, w1t, cls, Wq, bv, bo, q0, h_full, attn0, r0);
    k_conv  <<<1024, 256, 0, stream>>>(x, xb);
    k_u     <<<32,   256, 0, stream>>>(Wk, q0, bq, u);
    // -------- instrumentation probes (outputs overwritten by final k_gemm)
    k_gemm_probe<1><<<256, 256, 0, stream>>>(xb, w1t, b1, h_full);
    k_gemm_probe<2><<<256, 256, 0, stream>>>(xb, w1t, b1, h_full);
    k_gemm_probe<3><<<256, 256, 0, stream>>>(xb, w1t, b1, h_full);
    k_gemm_occ     <<<512, 256, 0, stream>>>(xb, w1t, b1, h_full);
    // -------- authoritative
    k_gemm  <<<256,  256, 0, stream>>>(xb, w1t, b1, u, h_full, scores);
    k_wsum  <<<256,  256, 0, stream>>>(scores, h_full, u, cls, svec);
    k_attn0 <<<32,   256, 0, stream>>>(svec, Wv, attn0);
    k_r0    <<<32,   256, 0, stream>>>(attn0, Wo, r0);
    k_final <<<1,    512, 0, stream>>>(r0, ln_g, ln_b, Wc, bc, out);
}